// Round 13
// baseline (132.052 us; speedup 1.0000x reference)
//
#include <hip/hip_runtime.h>
#include <math.h>

#define T_FR 400
#define B_SZ 8
#define NH   32
#define HOP  240
#define NBLK 1024

enum { ACT_NONE=0, ACT_RELU=1, ACT_BNRELU=2, ACT_SIG=3, ACT_TANHH=4 };

__device__ __forceinline__ float fast_tanh(float x)
{
    x = fminf(fmaxf(x, -9.f), 9.f);
    float e = __expf(2.f * x);
    return (e - 1.f) / (e + 1.f);
}

// write-through (device-coherent) stores/loads: relaxed agent-scope atomics
// operate at the coherence point; no fences, no cache-maintenance storms.
__device__ __forceinline__ void st_wt(float* p, float v)
{
    __hip_atomic_store(p, v, __ATOMIC_RELAXED, __HIP_MEMORY_SCOPE_AGENT);
}
__device__ __forceinline__ void st_wt2(float* p, float2 v)
{
    union { float2 f; unsigned long long u; } cv; cv.f = v;
    __hip_atomic_store((unsigned long long*)p, cv.u, __ATOMIC_RELAXED, __HIP_MEMORY_SCOPE_AGENT);
}
__device__ __forceinline__ void st_u32(unsigned* p, unsigned v)
{
    __hip_atomic_store(p, v, __ATOMIC_RELAXED, __HIP_MEMORY_SCOPE_AGENT);
}
__device__ __forceinline__ unsigned ld_u32(const unsigned* p)
{
    return __hip_atomic_load(p, __ATOMIC_RELAXED, __HIP_MEMORY_SCOPE_AGENT);
}

__device__ inline double shfl_up_dbl(double x, int off)
{
    long long v = __double_as_longlong(x);
    int lo = (int)(v & 0xffffffffLL);
    int hi = (int)(v >> 32);
    lo = __shfl_up(lo, off);
    hi = __shfl_up(hi, off);
    return __longlong_as_double(((long long)hi << 32) | (unsigned int)(unsigned)lo);
}

// ---- contention-free device barrier (flag array + leader scan).
// arrival = ONE write-through store per block (no RMW serialization).
// 16 leaders (blk%64==0) scan their group's 64 flags with pipelined
// independent loads; block 0 aggregates 16 gdone flags and posts 16
// release cells; members poll their group's release cell.
// All cells zeroed on-stream each launch (graph replay re-zeros).
__device__ __forceinline__ void gbar(unsigned* flags, unsigned* gdone,
                                     unsigned* rel, int blk)
{
    __syncthreads();
    if (threadIdx.x == 0) {
        st_u32(&flags[blk], 1u);
        const int g = blk >> 6;
        if ((blk & 63) == 0) {
            unsigned* fg = flags + (g << 6);
            int base = 0;
            for (int it = 0; it < (1 << 18) && base < 64; ++it) {
                unsigned all = 1u;
                #pragma unroll
                for (int j = 0; j < 16; ++j) all &= ld_u32(fg + base + j);
                if (all) { base += 16; it = 0; continue; }
                __builtin_amdgcn_s_sleep(2);
            }
            st_u32(&gdone[g * 16], 1u);
            if (blk == 0) {
                for (int it = 0; it < (1 << 18); ++it) {
                    unsigned all = 1u;
                    #pragma unroll
                    for (int q = 0; q < 16; ++q) all &= ld_u32(&gdone[q * 16]);
                    if (all) break;
                    __builtin_amdgcn_s_sleep(2);
                }
                #pragma unroll
                for (int q = 0; q < 16; ++q) st_u32(&rel[q * 16], 1u);
            }
        }
        for (int it = 0; it < (1 << 18); ++it) {
            if (ld_u32(&rel[g * 16])) break;
            __builtin_amdgcn_s_sleep(2);
        }
        asm volatile("" ::: "memory");   // compiler-only ordering
    }
    __syncthreads();
}

// ---------------- generic 3-tap conv task: 2 consecutive t per thread ----------------
// bi encodes (b, co-group) as b*nCoT + cog; callers pass XCD-affine b = task&7.
template<int CIN1, int CIN2, int COPT, int ACT>
__device__ __forceinline__ void conv_dev(
    int bi, const float* __restrict__ x1, const float* __restrict__ x2,
    const float* __restrict__ w, const float* __restrict__ bias,
    const float* __restrict__ g, const float* __restrict__ be,
    const float* __restrict__ mn, const float* __restrict__ vr,
    const float* __restrict__ voiced,
    float* __restrict__ y, int Cout)
{
    const int tid = (int)threadIdx.x;
    if (tid < 200) {
        const int CIN = CIN1 + CIN2;
        const int nCoT = Cout / COPT;
        const int b   = bi / nCoT;
        const int co0 = (bi - b * nCoT) * COPT;
        const int t0 = tid * 2;
        const bool has_m = (t0 > 0);
        const bool has_q = (t0 + 2 < T_FR);

        float acc[COPT][2];
        #pragma unroll
        for (int j = 0; j < COPT; ++j) { float bv = bias[co0 + j]; acc[j][0] = bv; acc[j][1] = bv; }

        {
            const float* xb = x1 + ((size_t)b * CIN1) * T_FR;
            #pragma unroll 4
            for (int ci = 0; ci < CIN1; ++ci) {
                const float* xr = xb + ci * T_FR;
                float xm = has_m ? xr[t0 - 1] : 0.f;
                float xc = xr[t0];
                float xp = xr[t0 + 1];
                float xq = has_q ? xr[t0 + 2] : 0.f;
                #pragma unroll
                for (int j = 0; j < COPT; ++j) {
                    const float* wr = w + ((size_t)(co0 + j) * CIN + ci) * 3;
                    float w0 = wr[0], w1 = wr[1], w2 = wr[2];
                    acc[j][0] = fmaf(xm, w0, fmaf(xc, w1, fmaf(xp, w2, acc[j][0])));
                    acc[j][1] = fmaf(xc, w0, fmaf(xp, w1, fmaf(xq, w2, acc[j][1])));
                }
            }
        }
        if constexpr (CIN2 > 0) {
            const float* xb = x2 + ((size_t)b * CIN2) * T_FR;
            #pragma unroll 4
            for (int ci = 0; ci < CIN2; ++ci) {
                const float* xr = xb + ci * T_FR;
                float xm = has_m ? xr[t0 - 1] : 0.f;
                float xc = xr[t0];
                float xp = xr[t0 + 1];
                float xq = has_q ? xr[t0 + 2] : 0.f;
                #pragma unroll
                for (int j = 0; j < COPT; ++j) {
                    const float* wr = w + ((size_t)(co0 + j) * CIN + CIN1 + ci) * 3;
                    float w0 = wr[0], w1 = wr[1], w2 = wr[2];
                    acc[j][0] = fmaf(xm, w0, fmaf(xc, w1, fmaf(xp, w2, acc[j][0])));
                    acc[j][1] = fmaf(xc, w0, fmaf(xp, w1, fmaf(xq, w2, acc[j][1])));
                }
            }
        }

        float2 vo;
        if (ACT == ACT_SIG) vo = *(const float2*)(voiced + (size_t)b * T_FR + t0);

        #pragma unroll
        for (int j = 0; j < COPT; ++j) {
            int co = co0 + j;
            float v0, v1;
            if (ACT == ACT_BNRELU) {
                float scale = g[co] * rsqrtf(vr[co] + 1e-5f);
                float sh = be[co] - mn[co] * scale;
                v0 = fmaxf(fmaf(acc[j][0], scale, sh), 0.f);
                v1 = fmaxf(fmaf(acc[j][1], scale, sh), 0.f);
            } else if (ACT == ACT_RELU) {
                v0 = fmaxf(acc[j][0], 0.f);
                v1 = fmaxf(acc[j][1], 0.f);
            } else if (ACT == ACT_SIG) {
                v0 = vo.x / (1.f + __expf(-acc[j][0])) + 1e-8f;
                v1 = vo.y / (1.f + __expf(-acc[j][1])) + 1e-8f;
            } else if (ACT == ACT_TANHH) {
                v0 = 0.5f * fast_tanh(acc[j][0]);
                v1 = 0.5f * fast_tanh(acc[j][1]);
            } else {
                v0 = acc[j][0]; v1 = acc[j][1];
            }
            float2 st = {v0, v1};
            st_wt2(y + ((size_t)b * Cout + co) * T_FR + t0, st);   // write-through
        }
    }
}

// ---------------- the whole pipeline in ONE kernel, 3 barriers ----------------
// XCD-affine: every task for batch b runs on blocks with blk%8==b.
__global__ __launch_bounds__(256, 4)
void mega_k(const float* mel, const float* f0, const float* voi,
            const float* w_f1, const float* b_f1,
            const float* w_f2, const float* b_f2,
            const float* w_a1, const float* b_a1,
            const float* g1, const float* be1, const float* m1, const float* v1,
            const float* w_a2, const float* b_a2,
            const float* g2, const float* be2, const float* m2, const float* v2,
            const float* w_a3, const float* b_a3,
            const float* w_p1, const float* b_p1,
            const float* w_p2, const float* b_p2,
            unsigned* bar, float* BMAX,
            float* F2, float* H1, float* H2, float* P1,
            float* INC, float* PREF, float* out)
{
    const int blk = (int)blockIdx.x;
    const int tid = (int)threadIdx.x;

    // barrier region layout (u32): flags[3][1024], gdone[3][16*16], rel[3][16*16]
    unsigned* flags0 = bar;
    unsigned* gdone0 = bar + 3*1024;
    unsigned* rel0   = bar + 3*1024 + 3*256;

    // =============== PHASE A: f0 scan (64) | fconv (40) | conv_a1 COPT=2 (512) ===============
    if (blk < 64) {
        __shared__ double sred[256];
        double s = 0.0;
        for (int i = tid; i < B_SZ*T_FR; i += 256) s += (double)f0[i];
        sred[tid] = s;
        __syncthreads();
        for (int off = 128; off > 0; off >>= 1) {
            if (tid < off) sred[tid] += sred[tid + off];
            __syncthreads();
        }
        const float mean = (float)(sred[0] / (double)(B_SZ*T_FR));

        const int b = blk & 7;                        // XCD-affine batch
        const int h = ((blk >> 3) << 2) + (tid >> 6); // 0..31
        const int wid  = (b << 5) + h;
        const int lane = tid & 63;
        const float n = (float)(h + 1);
        const float INV_SR = 1.0f / 22050.0f;

        float inc_loc[7];
        double local = 0.0;
        const int t0 = lane * 7;
        #pragma unroll
        for (int j = 0; j < 7; ++j) {
            int t = t0 + j;
            float iv = 0.f;
            if (t < T_FR) {
                float x  = f0[b*T_FR + t];
                float vv = voi[b*T_FR + t];
                float midi = 440.0f * exp2f((x - 69.0f) / 12.0f);
                float fz = (mean < 0.f) ? __expf(x) : ((mean < 50.f) ? midi : x);
                fz = fminf(fmaxf(fz, 50.f), 4000.f);
                fz = fz * vv + 100.f * (1.f - vv);
                iv = fminf(fz * n * INV_SR, 0.5f);   // rev units, >= 0
            }
            inc_loc[j] = iv;
            local += (double)iv;
        }
        local *= 240.0;

        double inc_sc = local;
        for (int off = 1; off < 64; off <<= 1) {
            double o = shfl_up_dbl(inc_sc, off);
            if (lane >= off) inc_sc += o;
        }
        double run = inc_sc - local;

        #pragma unroll
        for (int j = 0; j < 7; ++j) {
            int t = t0 + j;
            if (t < T_FR) {
                st_wt(&INC[wid*T_FR + t],  inc_loc[j]);
                st_wt(&PREF[wid*T_FR + t], (float)fmod(run, 1.0));
                run += (double)inc_loc[j] * 240.0;
            }
        }
    } else if (blk < 104) {
        const int tb = blk - 64;
        const int b  = tb & 7;                       // XCD-affine
        const int tg = (tb >> 3) * 80;
        __shared__ float xrow[84];
        __shared__ float f1s[16][84];

        if (tid < 84) {
            int t = tg - 2 + tid;
            xrow[tid] = (t >= 0 && t < T_FR) ? f0[b*T_FR + t] : 0.f;
        }
        __syncthreads();

        for (int i = tid; i < 16*82; i += 256) {
            int co = i / 82, u = i - co*82;
            int tau = tg - 1 + u;
            float a = b_f1[co];
            a = fmaf(xrow[u],   w_f1[co*3+0], a);
            a = fmaf(xrow[u+1], w_f1[co*3+1], a);
            a = fmaf(xrow[u+2], w_f1[co*3+2], a);
            f1s[co][u] = (tau >= 0 && tau < T_FR) ? fmaxf(a, 0.f) : 0.f;
        }
        __syncthreads();

        for (int i = tid; i < 16*80; i += 256) {
            int co = i / 80, v = i - co*80;
            float a = b_f2[co];
            #pragma unroll 4
            for (int ci = 0; ci < 16; ++ci) {
                const float* wr = w_f2 + (co*16 + ci)*3;
                a = fmaf(f1s[ci][v],   wr[0], a);
                a = fmaf(f1s[ci][v+1], wr[1], a);
                a = fmaf(f1s[ci][v+2], wr[2], a);
            }
            st_wt(&F2[(b*16 + co)*T_FR + tg + v], fmaxf(a, 0.f));
        }
    } else if (blk < 616) {
        const int t = blk - 104;                     // 104%8==0 -> t%8 == blk%8
        conv_dev<80,0,2,ACT_BNRELU>((t & 7) * 64 + (t >> 3), mel, nullptr, w_a1, b_a1,
                                    g1, be1, m1, v1, nullptr, H1, 128);
    }
    gbar(flags0 + 0*1024, gdone0 + 0*256, rel0 + 0*256, blk);

    // =============== PHASE B: conv_a2 COPT=2 (512) | conv_p1 COPT=1 (512) ===============
    if (blk < 512)
        conv_dev<128,0,2,ACT_BNRELU>((blk & 7) * 64 + (blk >> 3), H1, nullptr, w_a2, b_a2,
                                     g2, be2, m2, v2, nullptr, H2, 128);
    else {
        const int t = blk - 512;                     // t%8 == blk%8
        conv_dev<80,16,1,ACT_RELU>((t & 7) * 64 + (t >> 3), mel, F2, w_p1, b_p1,
                                   nullptr, nullptr, nullptr, nullptr, nullptr, P1, 64);
    }
    gbar(flags0 + 1*1024, gdone0 + 1*256, rel0 + 1*256, blk);

    // =============== PHASE D': LDS-gather + a3/p2 convs + synth + block max ===============
    const int b_s    = blk & 7;           // XCD-affine batch
    const int fgroup = blk >> 3;          // 0..127 ; frames t = fgroup + 128*i
    const int nf     = (fgroup < 16) ? 4 : 3;

    __shared__ float4 sp[4][NH];          // {inc, pref, amp, ph}
    __shared__ float H2t[4][3][128];      // H2 columns t-1,t,t+1 per frame
    __shared__ float P1t[4][3][64];       // P1 columns

    // gather INC/PREF (nf*64 <= 256 -> single pass)
    if (tid < nf*64) {
        int i = tid >> 6, r = tid & 63;
        int arr = r >> 5, h = r & 31;
        int t = fgroup + (i << 7);
        const float* src = arr ? PREF : INC;
        ((float*)&sp[i][h])[arr] = src[((b_s << 5) + h) * T_FR + t];
    }
    // gather H2 tile (no divisions: nested loops)
    #pragma unroll
    for (int i = 0; i < 4; ++i) {
        if (i < nf) {
            int tbase = fgroup + (i << 7);
            for (int v = tid; v < 384; v += 256) {
                int c = v >> 7, ci = v & 127;
                int col = tbase + c - 1;
                H2t[i][c][ci] = (col >= 0 && col < T_FR)
                                ? H2[((size_t)(b_s*128 + ci)) * T_FR + col] : 0.f;
            }
            if (tid < 192) {
                int c = tid >> 6, ci = tid & 63;
                int col = tbase + c - 1;
                P1t[i][c][ci] = (col >= 0 && col < T_FR)
                                ? P1[((size_t)(b_s*64 + ci)) * T_FR + col] : 0.f;
            }
        }
    }
    __syncthreads();

    // fused a3 (sigmoid*voiced) / p2 (tanh/2): one output per thread
    if (tid < nf*64) {
        int which = (tid >= nf*32);
        int idx = which ? tid - nf*32 : tid;
        int i = idx >> 5, h = idx & 31;
        int t = fgroup + (i << 7);
        if (!which) {
            const float* wr = w_a3 + (size_t)h * 384;
            float a = b_a3[h];
            #pragma unroll 8
            for (int ci = 0; ci < 128; ++ci) {
                a = fmaf(H2t[i][0][ci], wr[ci*3+0],
                    fmaf(H2t[i][1][ci], wr[ci*3+1],
                    fmaf(H2t[i][2][ci], wr[ci*3+2], a)));
            }
            sp[i][h].z = voi[b_s*T_FR + t] / (1.f + __expf(-a)) + 1e-8f;
        } else {
            const float* wr = w_p2 + (size_t)h * 192;
            float a = b_p2[h];
            #pragma unroll 8
            for (int ci = 0; ci < 64; ++ci) {
                a = fmaf(P1t[i][0][ci], wr[ci*3+0],
                    fmaf(P1t[i][1][ci], wr[ci*3+1],
                    fmaf(P1t[i][2][ci], wr[ci*3+2], a)));
            }
            sp[i][h].w = 0.5f * fast_tanh(a);
        }
    }
    __syncthreads();

    const float kf = (float)(tid + 1);
    float smp[4];
    float lmax = 0.f;
    #pragma unroll
    for (int i = 0; i < 4; ++i) {
        smp[i] = 0.f;
        if (i < nf) {
            float acc = 0.f;
            #pragma unroll 8
            for (int h = 0; h < NH; ++h) {
                float4 p = sp[i][h];                 // same-addr LDS broadcast
                float rev = fmaf(kf, p.x, p.y + p.w);
                rev -= floorf(rev);
                acc = fmaf(p.z, __builtin_amdgcn_sinf(rev), acc);
            }
            smp[i] = acc;
            if (tid < HOP) lmax = fmaxf(lmax, fabsf(acc));
        }
    }
    #pragma unroll
    for (int off = 32; off > 0; off >>= 1) lmax = fmaxf(lmax, __shfl_down(lmax, off));
    __shared__ float sm4[4];
    if ((tid & 63) == 0) sm4[tid >> 6] = lmax;
    __syncthreads();
    if (tid == 0)
        st_wt(&BMAX[(b_s << 7) + fgroup],
              fmaxf(fmaxf(sm4[0], sm4[1]), fmaxf(sm4[2], sm4[3])));
    gbar(flags0 + 2*1024, gdone0 + 2*256, rel0 + 2*256, blk);

    // =============== PHASE E: normalize from registers ===============
    const int lane = tid & 63;
    float m = fmaxf(BMAX[(b_s << 7) + lane], BMAX[(b_s << 7) + 64 + lane]);
    #pragma unroll
    for (int off = 32; off > 0; off >>= 1) m = fmaxf(m, __shfl_down(m, off));
    m = __shfl(m, 0);
    const float inv_wm = 1.f / fmaxf(m, 1e-8f);

    if (tid < HOP) {
        #pragma unroll
        for (int i = 0; i < 4; ++i) {
            if (i < nf) {
                int t = fgroup + (i << 7);
                out[(size_t)b_s * (T_FR*HOP) + t * HOP + tid] = fast_tanh(smp[i] * inv_wm);
            }
        }
    }
}

// ---------------- launch ----------------
extern "C" void kernel_launch(void* const* d_in, const int* in_sizes, int n_in,
                              void* d_out, int out_size, void* d_ws, size_t ws_size,
                              hipStream_t stream)
{
    const float* mel  = (const float*)d_in[0];
    const float* f0   = (const float*)d_in[1];
    const float* voi  = (const float*)d_in[2];
    const float* w_f1 = (const float*)d_in[3];  const float* b_f1 = (const float*)d_in[4];
    const float* w_f2 = (const float*)d_in[5];  const float* b_f2 = (const float*)d_in[6];
    const float* w_a1 = (const float*)d_in[7];  const float* b_a1 = (const float*)d_in[8];
    const float* g1   = (const float*)d_in[9];  const float* be1  = (const float*)d_in[10];
    const float* m1   = (const float*)d_in[11]; const float* v1   = (const float*)d_in[12];
    const float* w_a2 = (const float*)d_in[13]; const float* b_a2 = (const float*)d_in[14];
    const float* g2   = (const float*)d_in[15]; const float* be2  = (const float*)d_in[16];
    const float* m2   = (const float*)d_in[17]; const float* v2   = (const float*)d_in[18];
    const float* w_a3 = (const float*)d_in[19]; const float* b_a3 = (const float*)d_in[20];
    const float* w_p1 = (const float*)d_in[21]; const float* b_p1 = (const float*)d_in[22];
    const float* w_p2 = (const float*)d_in[23]; const float* b_p2 = (const float*)d_in[24];

    float* wsf = (float*)d_ws;
    unsigned* bar = (unsigned*)wsf;
    // u32 layout: flags 3*1024 | gdone 3*256 | rel 3*256  -> 4608 u32 = 18432 B
    const int bar_floats = 4608;
    float* BMAX = wsf + bar_floats;         // 1024
    float* F2   = BMAX + 1024;              // (8,16,400)
    float* H1   = F2   + 8*16*400;          // (8,128,400)
    float* H2   = H1   + 8*128*400;         // (8,128,400)
    float* P1   = H2   + 8*128*400;         // (8,64,400)
    float* INC  = P1   + 8*64*400;          // (8,32,400)  rev
    float* PREF = INC  + 8*32*400;          // (8,32,400)  rev

    // Barrier flags/cells MUST start at 0 each launch (graph replay re-runs this).
    hipMemsetAsync(bar, 0, 4608 * sizeof(unsigned), stream);

    mega_k<<<NBLK, 256, 0, stream>>>(mel, f0, voi,
                                     w_f1, b_f1, w_f2, b_f2,
                                     w_a1, b_a1, g1, be1, m1, v1,
                                     w_a2, b_a2, g2, be2, m2, v2,
                                     w_a3, b_a3, w_p1, b_p1, w_p2, b_p2,
                                     bar, BMAX,
                                     F2, H1, H2, P1, INC, PREF,
                                     (float*)d_out);
}

// Round 14
// 106.918 us; speedup vs baseline: 1.2351x; 1.2351x over previous
//
#include <hip/hip_runtime.h>
#include <math.h>

#define T_FR 400
#define B_SZ 8
#define NH   32
#define HOP  240

__device__ __forceinline__ float fast_tanh(float x)
{
    x = fminf(fmaxf(x, -9.f), 9.f);
    float e = __expf(2.f * x);
    return (e - 1.f) / (e + 1.f);
}

__device__ inline double shfl_up_dbl(double x, int off)
{
    long long v = __double_as_longlong(x);
    int lo = (int)(v & 0xffffffffLL);
    int hi = (int)(v >> 32);
    lo = __shfl_up(lo, off);
    hi = __shfl_up(hi, off);
    return __longlong_as_double(((long long)hi << 32) | (unsigned int)(unsigned)lo);
}

enum { ACT_RELU=1, ACT_BNRELU=2 };

// ---------------- generic 3-tap conv task: 2 consecutive t per thread ----------------
// bi encodes (b, co-group); normal cached stores (kernel boundary = coherence).
template<int CIN1, int CIN2, int COPT, int ACT>
__device__ __forceinline__ void conv_dev(
    int bi, const float* __restrict__ x1, const float* __restrict__ x2,
    const float* __restrict__ w, const float* __restrict__ bias,
    const float* __restrict__ g, const float* __restrict__ be,
    const float* __restrict__ mn, const float* __restrict__ vr,
    float* __restrict__ y, int Cout)
{
    const int tid = (int)threadIdx.x;
    if (tid < 200) {
        const int CIN = CIN1 + CIN2;
        const int nCoT = Cout / COPT;
        const int b   = bi / nCoT;
        const int co0 = (bi - b * nCoT) * COPT;
        const int t0 = tid * 2;
        const bool has_m = (t0 > 0);
        const bool has_q = (t0 + 2 < T_FR);

        float acc[COPT][2];
        #pragma unroll
        for (int j = 0; j < COPT; ++j) { float bv = bias[co0 + j]; acc[j][0] = bv; acc[j][1] = bv; }

        {
            const float* xb = x1 + ((size_t)b * CIN1) * T_FR;
            #pragma unroll 4
            for (int ci = 0; ci < CIN1; ++ci) {
                const float* xr = xb + ci * T_FR;
                float xm = has_m ? xr[t0 - 1] : 0.f;
                float xc = xr[t0];
                float xp = xr[t0 + 1];
                float xq = has_q ? xr[t0 + 2] : 0.f;
                #pragma unroll
                for (int j = 0; j < COPT; ++j) {
                    const float* wr = w + ((size_t)(co0 + j) * CIN + ci) * 3;
                    float w0 = wr[0], w1 = wr[1], w2 = wr[2];
                    acc[j][0] = fmaf(xm, w0, fmaf(xc, w1, fmaf(xp, w2, acc[j][0])));
                    acc[j][1] = fmaf(xc, w0, fmaf(xp, w1, fmaf(xq, w2, acc[j][1])));
                }
            }
        }
        if constexpr (CIN2 > 0) {
            const float* xb = x2 + ((size_t)b * CIN2) * T_FR;
            #pragma unroll 4
            for (int ci = 0; ci < CIN2; ++ci) {
                const float* xr = xb + ci * T_FR;
                float xm = has_m ? xr[t0 - 1] : 0.f;
                float xc = xr[t0];
                float xp = xr[t0 + 1];
                float xq = has_q ? xr[t0 + 2] : 0.f;
                #pragma unroll
                for (int j = 0; j < COPT; ++j) {
                    const float* wr = w + ((size_t)(co0 + j) * CIN + CIN1 + ci) * 3;
                    float w0 = wr[0], w1 = wr[1], w2 = wr[2];
                    acc[j][0] = fmaf(xm, w0, fmaf(xc, w1, fmaf(xp, w2, acc[j][0])));
                    acc[j][1] = fmaf(xc, w0, fmaf(xp, w1, fmaf(xq, w2, acc[j][1])));
                }
            }
        }

        #pragma unroll
        for (int j = 0; j < COPT; ++j) {
            int co = co0 + j;
            float v0, v1;
            if (ACT == ACT_BNRELU) {
                float scale = g[co] * rsqrtf(vr[co] + 1e-5f);
                float sh = be[co] - mn[co] * scale;
                v0 = fmaxf(fmaf(acc[j][0], scale, sh), 0.f);
                v1 = fmaxf(fmaf(acc[j][1], scale, sh), 0.f);
            } else {
                v0 = fmaxf(acc[j][0], 0.f);
                v1 = fmaxf(acc[j][1], 0.f);
            }
            float2 st = {v0, v1};
            *(float2*)(y + ((size_t)b * Cout + co) * T_FR + t0) = st;
        }
    }
}

// =============== K1: f0 scan (64) | fconv (40) | conv_a1 COPT=2 (512) ===============
__global__ __launch_bounds__(256)
void k1(const float* __restrict__ f0, const float* __restrict__ voi,
        const float* __restrict__ mel,
        const float* __restrict__ w_f1, const float* __restrict__ b_f1,
        const float* __restrict__ w_f2, const float* __restrict__ b_f2,
        const float* __restrict__ w_a1, const float* __restrict__ b_a1,
        const float* __restrict__ g1, const float* __restrict__ be1,
        const float* __restrict__ m1, const float* __restrict__ v1,
        float* __restrict__ INC, float* __restrict__ PREF,
        float* __restrict__ F2, float* __restrict__ H1,
        unsigned* __restrict__ wmax8)
{
    const int blk = (int)blockIdx.x;
    const int tid = (int)threadIdx.x;

    if (blk == 0 && tid < B_SZ) wmax8[tid] = 0u;   // K3's atomicMax targets

    if (blk < 64) {
        __shared__ double sred[256];
        double s = 0.0;
        for (int i = tid; i < B_SZ*T_FR; i += 256) s += (double)f0[i];
        sred[tid] = s;
        __syncthreads();
        for (int off = 128; off > 0; off >>= 1) {
            if (tid < off) sred[tid] += sred[tid + off];
            __syncthreads();
        }
        const float mean = (float)(sred[0] / (double)(B_SZ*T_FR));

        const int b = blk & 7;
        const int h = ((blk >> 3) << 2) + (tid >> 6);   // 0..31
        const int wid  = (b << 5) + h;
        const int lane = tid & 63;
        const float n = (float)(h + 1);
        const float INV_SR = 1.0f / 22050.0f;

        float inc_loc[7];
        double local = 0.0;
        const int t0 = lane * 7;
        #pragma unroll
        for (int j = 0; j < 7; ++j) {
            int t = t0 + j;
            float iv = 0.f;
            if (t < T_FR) {
                float x  = f0[b*T_FR + t];
                float vv = voi[b*T_FR + t];
                float midi = 440.0f * exp2f((x - 69.0f) / 12.0f);
                float fz = (mean < 0.f) ? __expf(x) : ((mean < 50.f) ? midi : x);
                fz = fminf(fmaxf(fz, 50.f), 4000.f);
                fz = fz * vv + 100.f * (1.f - vv);
                iv = fminf(fz * n * INV_SR, 0.5f);   // rev units, >= 0
            }
            inc_loc[j] = iv;
            local += (double)iv;
        }
        local *= 240.0;

        double inc_sc = local;
        for (int off = 1; off < 64; off <<= 1) {
            double o = shfl_up_dbl(inc_sc, off);
            if (lane >= off) inc_sc += o;
        }
        double run = inc_sc - local;

        #pragma unroll
        for (int j = 0; j < 7; ++j) {
            int t = t0 + j;
            if (t < T_FR) {
                INC[wid*T_FR + t]  = inc_loc[j];
                PREF[wid*T_FR + t] = (float)fmod(run, 1.0);
                run += (double)inc_loc[j] * 240.0;
            }
        }
    } else if (blk < 104) {
        const int tb = blk - 64;
        const int b  = tb & 7;
        const int tg = (tb >> 3) * 80;
        __shared__ float xrow[84];
        __shared__ float f1s[16][84];

        if (tid < 84) {
            int t = tg - 2 + tid;
            xrow[tid] = (t >= 0 && t < T_FR) ? f0[b*T_FR + t] : 0.f;
        }
        __syncthreads();

        for (int i = tid; i < 16*82; i += 256) {
            int co = i / 82, u = i - co*82;
            int tau = tg - 1 + u;
            float a = b_f1[co];
            a = fmaf(xrow[u],   w_f1[co*3+0], a);
            a = fmaf(xrow[u+1], w_f1[co*3+1], a);
            a = fmaf(xrow[u+2], w_f1[co*3+2], a);
            f1s[co][u] = (tau >= 0 && tau < T_FR) ? fmaxf(a, 0.f) : 0.f;
        }
        __syncthreads();

        for (int i = tid; i < 16*80; i += 256) {
            int co = i / 80, v = i - co*80;
            float a = b_f2[co];
            #pragma unroll 4
            for (int ci = 0; ci < 16; ++ci) {
                const float* wr = w_f2 + (co*16 + ci)*3;
                a = fmaf(f1s[ci][v],   wr[0], a);
                a = fmaf(f1s[ci][v+1], wr[1], a);
                a = fmaf(f1s[ci][v+2], wr[2], a);
            }
            F2[(b*16 + co)*T_FR + tg + v] = fmaxf(a, 0.f);
        }
    } else {
        const int t = blk - 104;   // 0..511
        conv_dev<80,0,2,ACT_BNRELU>((t & 7) * 64 + (t >> 3), mel, nullptr, w_a1, b_a1,
                                    g1, be1, m1, v1, H1, 128);
    }
}

// =============== K2: conv_a2 COPT=2 (512) | conv_p1 COPT=1 (512) ===============
__global__ __launch_bounds__(256)
void k2(const float* __restrict__ H1, const float* __restrict__ mel,
        const float* __restrict__ F2,
        const float* __restrict__ w_a2, const float* __restrict__ b_a2,
        const float* __restrict__ g2, const float* __restrict__ be2,
        const float* __restrict__ m2, const float* __restrict__ v2,
        const float* __restrict__ w_p1, const float* __restrict__ b_p1,
        float* __restrict__ H2, float* __restrict__ P1)
{
    const int blk = (int)blockIdx.x;
    if (blk < 512)
        conv_dev<128,0,2,ACT_BNRELU>((blk & 7) * 64 + (blk >> 3), H1, nullptr, w_a2, b_a2,
                                     g2, be2, m2, v2, H2, 128);
    else {
        const int t = blk - 512;
        conv_dev<80,16,1,ACT_RELU>((t & 7) * 64 + (t >> 3), mel, F2, w_p1, b_p1,
                                   nullptr, nullptr, nullptr, nullptr, P1, 64);
    }
}

// =============== K3: LDS-gather + a3/p2 convs + synth + per-batch atomicMax ===============
__global__ __launch_bounds__(256)
void k3(const float* __restrict__ H2, const float* __restrict__ P1,
        const float* __restrict__ voi,
        const float* __restrict__ w_a3, const float* __restrict__ b_a3,
        const float* __restrict__ w_p2, const float* __restrict__ b_p2,
        const float* __restrict__ INC, const float* __restrict__ PREF,
        float* __restrict__ wave, unsigned* __restrict__ wmax8)
{
    const int blk = (int)blockIdx.x;
    const int tid = (int)threadIdx.x;
    const int b_s    = blk & 7;
    const int fgroup = blk >> 3;          // 0..127 ; frames t = fgroup + 128*i
    const int nf     = (fgroup < 16) ? 4 : 3;

    __shared__ float4 sp[4][NH];          // {inc, pref, amp, ph}
    __shared__ float H2t[4][3][128];
    __shared__ float P1t[4][3][64];

    if (tid < nf*64) {
        int i = tid >> 6, r = tid & 63;
        int arr = r >> 5, h = r & 31;
        int t = fgroup + (i << 7);
        const float* src = arr ? PREF : INC;
        ((float*)&sp[i][h])[arr] = src[((b_s << 5) + h) * T_FR + t];
    }
    #pragma unroll
    for (int i = 0; i < 4; ++i) {
        if (i < nf) {
            int tbase = fgroup + (i << 7);
            for (int v = tid; v < 384; v += 256) {
                int c = v >> 7, ci = v & 127;
                int col = tbase + c - 1;
                H2t[i][c][ci] = (col >= 0 && col < T_FR)
                                ? H2[((size_t)(b_s*128 + ci)) * T_FR + col] : 0.f;
            }
            if (tid < 192) {
                int c = tid >> 6, ci = tid & 63;
                int col = tbase + c - 1;
                P1t[i][c][ci] = (col >= 0 && col < T_FR)
                                ? P1[((size_t)(b_s*64 + ci)) * T_FR + col] : 0.f;
            }
        }
    }
    __syncthreads();

    if (tid < nf*64) {
        int which = (tid >= nf*32);
        int idx = which ? tid - nf*32 : tid;
        int i = idx >> 5, h = idx & 31;
        int t = fgroup + (i << 7);
        if (!which) {
            const float* wr = w_a3 + (size_t)h * 384;
            float a = b_a3[h];
            #pragma unroll 8
            for (int ci = 0; ci < 128; ++ci) {
                a = fmaf(H2t[i][0][ci], wr[ci*3+0],
                    fmaf(H2t[i][1][ci], wr[ci*3+1],
                    fmaf(H2t[i][2][ci], wr[ci*3+2], a)));
            }
            sp[i][h].z = voi[b_s*T_FR + t] / (1.f + __expf(-a)) + 1e-8f;
        } else {
            const float* wr = w_p2 + (size_t)h * 192;
            float a = b_p2[h];
            #pragma unroll 8
            for (int ci = 0; ci < 64; ++ci) {
                a = fmaf(P1t[i][0][ci], wr[ci*3+0],
                    fmaf(P1t[i][1][ci], wr[ci*3+1],
                    fmaf(P1t[i][2][ci], wr[ci*3+2], a)));
            }
            sp[i][h].w = 0.5f * fast_tanh(a);
        }
    }
    __syncthreads();

    const float kf = (float)(tid + 1);
    float lmax = 0.f;
    #pragma unroll
    for (int i = 0; i < 4; ++i) {
        if (i < nf) {
            int t = fgroup + (i << 7);
            float acc = 0.f;
            #pragma unroll 8
            for (int h = 0; h < NH; ++h) {
                float4 p = sp[i][h];                 // same-addr LDS broadcast
                float rev = fmaf(kf, p.x, p.y + p.w);
                rev -= floorf(rev);
                acc = fmaf(p.z, __builtin_amdgcn_sinf(rev), acc);
            }
            if (tid < HOP) {
                wave[((size_t)b_s * T_FR + t) * HOP + tid] = acc;
                lmax = fmaxf(lmax, fabsf(acc));
            }
        }
    }
    #pragma unroll
    for (int off = 32; off > 0; off >>= 1) lmax = fmaxf(lmax, __shfl_down(lmax, off));
    __shared__ float sm4[4];
    if ((tid & 63) == 0) sm4[tid >> 6] = lmax;
    __syncthreads();
    if (tid == 0) {
        float m = fmaxf(fmaxf(sm4[0], sm4[1]), fmaxf(sm4[2], sm4[3]));
        atomicMax(&wmax8[b_s], __float_as_uint(m));   // |wave| >= 0: uint-bit max == float max
    }
}

// =============== K4: float4 tanh-normalize ===============
__global__ __launch_bounds__(256)
void k4(const float* __restrict__ wave, const unsigned* __restrict__ wmax8,
        float* __restrict__ out)
{
    const int idx4 = (int)(blockIdx.x * 256 + threadIdx.x);   // 0..191999
    const int s = idx4 * 4;
    const int b = s / (T_FR * HOP);
    const float inv_wm = 1.f / fmaxf(__uint_as_float(wmax8[b]), 1e-8f);

    float4 v = *(const float4*)(wave + s);
    float4 o;
    o.x = fast_tanh(v.x * inv_wm);
    o.y = fast_tanh(v.y * inv_wm);
    o.z = fast_tanh(v.z * inv_wm);
    o.w = fast_tanh(v.w * inv_wm);
    *(float4*)(out + s) = o;
}

// ---------------- launch ----------------
extern "C" void kernel_launch(void* const* d_in, const int* in_sizes, int n_in,
                              void* d_out, int out_size, void* d_ws, size_t ws_size,
                              hipStream_t stream)
{
    const float* mel  = (const float*)d_in[0];
    const float* f0   = (const float*)d_in[1];
    const float* voi  = (const float*)d_in[2];
    const float* w_f1 = (const float*)d_in[3];  const float* b_f1 = (const float*)d_in[4];
    const float* w_f2 = (const float*)d_in[5];  const float* b_f2 = (const float*)d_in[6];
    const float* w_a1 = (const float*)d_in[7];  const float* b_a1 = (const float*)d_in[8];
    const float* g1   = (const float*)d_in[9];  const float* be1  = (const float*)d_in[10];
    const float* m1   = (const float*)d_in[11]; const float* v1   = (const float*)d_in[12];
    const float* w_a2 = (const float*)d_in[13]; const float* b_a2 = (const float*)d_in[14];
    const float* g2   = (const float*)d_in[15]; const float* be2  = (const float*)d_in[16];
    const float* m2   = (const float*)d_in[17]; const float* v2   = (const float*)d_in[18];
    const float* w_a3 = (const float*)d_in[19]; const float* b_a3 = (const float*)d_in[20];
    const float* w_p1 = (const float*)d_in[21]; const float* b_p1 = (const float*)d_in[22];
    const float* w_p2 = (const float*)d_in[23]; const float* b_p2 = (const float*)d_in[24];

    float* wsf = (float*)d_ws;
    unsigned* wmax8 = (unsigned*)wsf;       // 8 u32 (zeroed by K1)
    float* F2   = wsf + 16;                 // (8,16,400)
    float* H1   = F2   + 8*16*400;          // (8,128,400)
    float* H2   = H1   + 8*128*400;         // (8,128,400)
    float* P1   = H2   + 8*128*400;         // (8,64,400)
    float* INC  = P1   + 8*64*400;          // (8,32,400)  rev
    float* PREF = INC  + 8*32*400;          // (8,32,400)  rev
    float* WAVE = PREF + 8*32*400;          // (8,96000)

    k1<<<616, 256, 0, stream>>>(f0, voi, mel, w_f1, b_f1, w_f2, b_f2,
                                w_a1, b_a1, g1, be1, m1, v1,
                                INC, PREF, F2, H1, wmax8);
    k2<<<1024, 256, 0, stream>>>(H1, mel, F2, w_a2, b_a2, g2, be2, m2, v2,
                                 w_p1, b_p1, H2, P1);
    k3<<<1024, 256, 0, stream>>>(H2, P1, voi, w_a3, b_a3, w_p2, b_p2,
                                 INC, PREF, WAVE, wmax8);
    k4<<<750, 256, 0, stream>>>(WAVE, wmax8, (float*)d_out);
}